// Round 6
// baseline (100.230 us; speedup 1.0000x reference)
//
#include <hip/hip_runtime.h>

// Problem constants (B,C,H,W,K) = (32,192,56,56,7)
#define BB 32
#define CC 192
#define HH 56
#define WW 56
#define KS 7
#define HW 3136        // 56*56
#define KK 49
#define CKK 9408       // C*K*K
#define PL 8
#define NCELL (BB * CC * KK)   // 301056 = 1176*256
#define NBC (BB * CC)          // 6144
#define SPAD 32                // stats padding: one 128B line per sample

// ---------------------------------------------------------------------------
// K1: avg pool 56x56 -> 7x7. Pure streaming, no atomics.
// ---------------------------------------------------------------------------
__global__ __launch_bounds__(256) void pool_kernel(const float* __restrict__ x,
                                                   float* __restrict__ p0) {
    int idx = blockIdx.x * 256 + threadIdx.x;
    int j = idx % KS;
    int i = (idx / KS) % KS;
    int bc = idx / KK;
    const float* src = x + (size_t)bc * HW + (i * PL) * WW + j * PL;
    float s = 0.f;
#pragma unroll
    for (int a = 0; a < PL; ++a) {
        float4 v0 = *(const float4*)(src + a * WW);
        float4 v1 = *(const float4*)(src + a * WW + 4);
        s += v0.x + v0.y + v0.z + v0.w + v1.x + v1.y + v1.z + v1.w;
    }
    p0[idx] = s * (1.f / 64.f);
}

// ---------------------------------------------------------------------------
// K2: LN0 stats. Block t reduces p0[t*1176 .. +1176); 8 blocks per sample.
// ---------------------------------------------------------------------------
__global__ __launch_bounds__(256) void stats0_kernel(const float* __restrict__ p0,
                                                     float* __restrict__ stats0) {
    __shared__ float red[8];
    int t = blockIdx.x;
    int b = t >> 3;
    const float* src = p0 + t * 1176;
    float s = 0.f, ss = 0.f;
    for (int i = threadIdx.x; i < 1176; i += 256) {
        float v = src[i];
        s += v; ss += v * v;
    }
#pragma unroll
    for (int o = 32; o > 0; o >>= 1) {
        s  += __shfl_down(s, o, 64);
        ss += __shfl_down(ss, o, 64);
    }
    if ((threadIdx.x & 63) == 0) {
        red[(threadIdx.x >> 6) * 2 + 0] = s;
        red[(threadIdx.x >> 6) * 2 + 1] = ss;
    }
    __syncthreads();
    if (threadIdx.x == 0) {
        atomicAdd(&stats0[b * SPAD + 0], red[0] + red[2] + red[4] + red[6]);
        atomicAdd(&stats0[b * SPAD + 1], red[1] + red[3] + red[5] + red[7]);
    }
}

// ---------------------------------------------------------------------------
// K3: LN0-normalize + depthwise 7x7 conv on the 7x7 map, one WAVE per (b,c).
// Produces raw conv output q1 + LN1 stats (padded atomics).
// ---------------------------------------------------------------------------
__global__ __launch_bounds__(512) void mid_kernel(
    const float* __restrict__ p0,
    const float* __restrict__ ln0w, const float* __restrict__ ln0b,
    const float* __restrict__ w0,
    const float* __restrict__ stats0,
    float* __restrict__ q1,
    float* __restrict__ stats1)
{
    int tid  = threadIdx.x;
    int lane = tid & 63;
    int bc   = blockIdx.x * 8 + (tid >> 6);
    int b = bc / CC;
    int c = bc - b * CC;

    float s0   = stats0[b * SPAD + 0];
    float ss0  = stats0[b * SPAD + 1];
    float mean = s0 * (1.f / CKK);
    float rstd = rsqrtf(ss0 * (1.f / CKK) - mean * mean + 1e-5f);

    float val = 0.f;
    if (lane < KK)
        val = (p0[bc * KK + lane] - mean) * rstd * ln0w[c * KK + lane]
              + ln0b[c * KK + lane];

    int i0 = lane / KS;
    int j0 = lane - i0 * KS;
    const float* wc = w0 + c * KK;

    float acc = 0.f;
#pragma unroll
    for (int u = 0; u < KS; ++u) {
        int ii = i0 + u - 3;
#pragma unroll
        for (int v = 0; v < KS; ++v) {
            int jj = j0 + v - 3;
            bool ok = (ii >= 0) && (ii < KS) && (jj >= 0) && (jj < KS);
            int sl = ok ? (ii * KS + jj) : 0;
            float sv = __shfl(val, sl, 64);
            acc += ok ? sv * wc[u * KS + v] : 0.f;
        }
    }
    if (lane >= KK) acc = 0.f;
    if (lane < KK) q1[bc * KK + lane] = acc;

    float s2 = acc, ss2 = acc * acc;
#pragma unroll
    for (int o = 32; o > 0; o >>= 1) {
        s2  += __shfl_down(s2, o, 64);
        ss2 += __shfl_down(ss2, o, 64);
    }
    if (lane == 0) {
        atomicAdd(&stats1[b * SPAD + 0], s2);
        atomicAdd(&stats1[b * SPAD + 1], ss2);
    }
}

// ---------------------------------------------------------------------------
// K4: fused LN1+ReLU taps + per-(b,c) depthwise 7x7 SAME conv.
// Zero-halo LDS tile [62][64]. Lane = (cp 0..13, rg 0..3); each lane computes
// a 4-row x 4-col output patch. Per input row: 3x 16B-aligned ds_read_b128
// (12 floats) feed 112 fmacs. Row-starts {0,4,7,10} overlap -> no divergence
// (duplicated rows produce bit-identical stores).
// ---------------------------------------------------------------------------
#define TILEW 64
#define TILEH 62

__device__ __forceinline__ float rfl(float v) {
    return __int_as_float(__builtin_amdgcn_readfirstlane(__float_as_int(v)));
}

__global__ __launch_bounds__(256) void conv_kernel(
    const float* __restrict__ x,
    const float* __restrict__ q1, const float* __restrict__ stats1,
    const float* __restrict__ ln1w, const float* __restrict__ ln1b,
    float* __restrict__ out)
{
    __shared__ float tile[TILEH * TILEW];   // tile[r][c] = x[r-3][c-4], 0 outside
    __shared__ float kt[KK];
    int bc   = blockIdx.x;
    int b    = bc / CC;
    int c    = bc - b * CC;
    int tid  = threadIdx.x;
    int lane = tid & 63;
    int wid  = tid >> 6;

    // ---- taps: LN1 + ReLU on q1 ----
    if (tid < KK) {
        float s1  = stats1[b * SPAD + 0];
        float ss1 = stats1[b * SPAD + 1];
        float m = s1 * (1.f / CKK);
        float r = rsqrtf(ss1 * (1.f / CKK) - m * m + 1e-5f);
        float v = (q1[(size_t)bc * KK + tid] - m) * r * ln1w[c * KK + tid]
                  + ln1b[c * KK + tid];
        kt[tid] = v > 0.f ? v : 0.f;
    }

    // ---- zero halo: rows 0-2 & 59-61 full width; cols 0-3 & 60-63 ----
    if (tid < 96) {
        int r = tid >> 4;
        int q = tid & 15;
        int row = r < 3 ? r : 56 + r;      // 0,1,2,59,60,61
        *(float4*)(tile + row * TILEW + q * 4) = make_float4(0.f, 0.f, 0.f, 0.f);
    } else if (tid < 152) {
        *(float4*)(tile + (tid - 96 + 3) * TILEW) = make_float4(0.f, 0.f, 0.f, 0.f);
    } else if (tid < 208) {
        *(float4*)(tile + (tid - 152 + 3) * TILEW + 60) = make_float4(0.f, 0.f, 0.f, 0.f);
    }

    // ---- stage interior: x[r][0..55] -> tile[r+3][4..59] ----
    const float* src = x + (size_t)bc * HW;
    for (int i = tid; i < HH * 14; i += 256) {
        int r = i / 14;
        int q = i - r * 14;
        *(float4*)(tile + (r + 3) * TILEW + 4 + q * 4) =
            *(const float4*)(src + r * WW + q * 4);
    }
    __syncthreads();

    // ---- taps -> SGPRs ----
    float tap[KK];
#pragma unroll
    for (int t = 0; t < KK; ++t) tap[t] = rfl(kt[t]);

    // ---- lane mapping: cp = column group, rg = row group ----
    int rg = lane / 14; if (rg > 3) rg = 3;     // lanes 56-63 duplicate rg3
    int cp = lane - rg * 14; if (cp > 13) cp = lane - 56;  // (rg clamped case)
    int sl = rg == 0 ? 0 : (rg == 1 ? 4 : (rg == 2 ? 7 : 10));
    int o0 = wid * 14 + sl;                     // first output row of this lane
    const float* tb = tile + o0 * TILEW + 4 * cp;

    float acc[4][4];
#pragma unroll
    for (int t = 0; t < 4; ++t)
#pragma unroll
        for (int c4 = 0; c4 < 4; ++c4) acc[t][c4] = 0.f;

#pragma unroll
    for (int k = 0; k < 10; ++k) {
        float4 A = *(const float4*)(tb + k * TILEW);
        float4 Bv = *(const float4*)(tb + k * TILEW + 4);
        float4 Cv = *(const float4*)(tb + k * TILEW + 8);
        float w[12];
        w[0] = A.x;  w[1] = A.y;  w[2] = A.z;  w[3] = A.w;
        w[4] = Bv.x; w[5] = Bv.y; w[6] = Bv.z; w[7] = Bv.w;
        w[8] = Cv.x; w[9] = Cv.y; w[10] = Cv.z; w[11] = Cv.w;
#pragma unroll
        for (int t = 0; t < 4; ++t) {
            int u = k - t;                      // static after unroll
            if (u >= 0 && u < KS) {
#pragma unroll
                for (int dv = 0; dv < KS; ++dv) {
                    float kv = tap[u * KS + dv];
#pragma unroll
                    for (int c4 = 0; c4 < 4; ++c4)
                        acc[t][c4] = fmaf(w[c4 + dv + 1], kv, acc[t][c4]);
                }
            }
        }
    }

    float* ob = out + (size_t)bc * HW;
#pragma unroll
    for (int t = 0; t < 4; ++t) {
        *(float4*)(ob + (o0 + t) * WW + 4 * cp) =
            make_float4(acc[t][0], acc[t][1], acc[t][2], acc[t][3]);
    }
}

// ---------------------------------------------------------------------------
extern "C" void kernel_launch(void* const* d_in, const int* in_sizes, int n_in,
                              void* d_out, int out_size, void* d_ws, size_t ws_size,
                              hipStream_t stream) {
    const float* x    = (const float*)d_in[0];
    const float* ln0w = (const float*)d_in[1];
    const float* ln0b = (const float*)d_in[2];
    const float* w0   = (const float*)d_in[3];
    const float* ln1w = (const float*)d_in[4];
    const float* ln1b = (const float*)d_in[5];
    float* out = (float*)d_out;

    float* p0     = (float*)d_ws;          // [NCELL]
    float* q1     = p0 + NCELL;            // [NCELL]
    float* stats0 = q1 + NCELL;            // [BB*SPAD]
    float* stats1 = stats0 + BB * SPAD;    // [BB*SPAD]

    hipMemsetAsync(stats0, 0, 2 * BB * SPAD * sizeof(float), stream);
    pool_kernel  <<<NCELL / 256, 256, 0, stream>>>(x, p0);
    stats0_kernel<<<BB * 8, 256, 0, stream>>>(p0, stats0);
    mid_kernel   <<<NBC / 8, 512, 0, stream>>>(p0, ln0w, ln0b, w0, stats0, q1, stats1);
    conv_kernel  <<<NBC, 256, 0, stream>>>(x, q1, stats1, ln1w, ln1b, out);
}

// Round 7
// 86.194 us; speedup vs baseline: 1.1628x; 1.1628x over previous
//
#include <hip/hip_runtime.h>

// Problem constants (B,C,H,W,K) = (32,192,56,56,7)
#define BB 32
#define CC 192
#define HH 56
#define WW 56
#define KS 7
#define HW 3136        // 56*56
#define KK 49
#define CKK 9408       // C*K*K
#define PL 8
#define NCELL (BB * CC * KK)   // 301056 = 1176*256
#define NBC (BB * CC)          // 6144
#define SPAD 32                // stats padding: one 128B line per sample

// ---------------------------------------------------------------------------
// K1: avg pool 56x56 -> 7x7. Pure streaming, no atomics.
// ---------------------------------------------------------------------------
__global__ __launch_bounds__(256) void pool_kernel(const float* __restrict__ x,
                                                   float* __restrict__ p0) {
    int idx = blockIdx.x * 256 + threadIdx.x;
    int j = idx % KS;
    int i = (idx / KS) % KS;
    int bc = idx / KK;
    const float* src = x + (size_t)bc * HW + (i * PL) * WW + j * PL;
    float s = 0.f;
#pragma unroll
    for (int a = 0; a < PL; ++a) {
        float4 v0 = *(const float4*)(src + a * WW);
        float4 v1 = *(const float4*)(src + a * WW + 4);
        s += v0.x + v0.y + v0.z + v0.w + v1.x + v1.y + v1.z + v1.w;
    }
    p0[idx] = s * (1.f / 64.f);
}

// ---------------------------------------------------------------------------
// K2: LN0 stats. Block t reduces p0[t*1176 .. +1176); 8 blocks per sample.
// ---------------------------------------------------------------------------
__global__ __launch_bounds__(256) void stats0_kernel(const float* __restrict__ p0,
                                                     float* __restrict__ stats0) {
    __shared__ float red[8];
    int t = blockIdx.x;
    int b = t >> 3;
    const float* src = p0 + t * 1176;
    float s = 0.f, ss = 0.f;
    for (int i = threadIdx.x; i < 1176; i += 256) {
        float v = src[i];
        s += v; ss += v * v;
    }
#pragma unroll
    for (int o = 32; o > 0; o >>= 1) {
        s  += __shfl_down(s, o, 64);
        ss += __shfl_down(ss, o, 64);
    }
    if ((threadIdx.x & 63) == 0) {
        red[(threadIdx.x >> 6) * 2 + 0] = s;
        red[(threadIdx.x >> 6) * 2 + 1] = ss;
    }
    __syncthreads();
    if (threadIdx.x == 0) {
        atomicAdd(&stats0[b * SPAD + 0], red[0] + red[2] + red[4] + red[6]);
        atomicAdd(&stats0[b * SPAD + 1], red[1] + red[3] + red[5] + red[7]);
    }
}

// ---------------------------------------------------------------------------
// K3: LN0-normalize + depthwise 7x7 conv on the 7x7 map, one WAVE per (b,c).
// Produces raw conv output q1 + LN1 stats (padded atomics).
// ---------------------------------------------------------------------------
__global__ __launch_bounds__(512) void mid_kernel(
    const float* __restrict__ p0,
    const float* __restrict__ ln0w, const float* __restrict__ ln0b,
    const float* __restrict__ w0,
    const float* __restrict__ stats0,
    float* __restrict__ q1,
    float* __restrict__ stats1)
{
    int tid  = threadIdx.x;
    int lane = tid & 63;
    int bc   = blockIdx.x * 8 + (tid >> 6);
    int b = bc / CC;
    int c = bc - b * CC;

    float s0   = stats0[b * SPAD + 0];
    float ss0  = stats0[b * SPAD + 1];
    float mean = s0 * (1.f / CKK);
    float rstd = rsqrtf(ss0 * (1.f / CKK) - mean * mean + 1e-5f);

    float val = 0.f;
    if (lane < KK)
        val = (p0[bc * KK + lane] - mean) * rstd * ln0w[c * KK + lane]
              + ln0b[c * KK + lane];

    int i0 = lane / KS;
    int j0 = lane - i0 * KS;
    const float* wc = w0 + c * KK;

    float acc = 0.f;
#pragma unroll
    for (int u = 0; u < KS; ++u) {
        int ii = i0 + u - 3;
#pragma unroll
        for (int v = 0; v < KS; ++v) {
            int jj = j0 + v - 3;
            bool ok = (ii >= 0) && (ii < KS) && (jj >= 0) && (jj < KS);
            int sl = ok ? (ii * KS + jj) : 0;
            float sv = __shfl(val, sl, 64);
            acc += ok ? sv * wc[u * KS + v] : 0.f;
        }
    }
    if (lane >= KK) acc = 0.f;
    if (lane < KK) q1[bc * KK + lane] = acc;

    float s2 = acc, ss2 = acc * acc;
#pragma unroll
    for (int o = 32; o > 0; o >>= 1) {
        s2  += __shfl_down(s2, o, 64);
        ss2 += __shfl_down(ss2, o, 64);
    }
    if (lane == 0) {
        atomicAdd(&stats1[b * SPAD + 0], s2);
        atomicAdd(&stats1[b * SPAD + 1], ss2);
    }
}

// ---------------------------------------------------------------------------
// K4: fused LN1+ReLU taps + per-(b,c) depthwise 7x7 SAME conv.
// Zero-halo LDS tile [62][64] with LEFT PAD 3: tile[r][c] = x[r-3][c-3].
// Lane = (cp 0..27, rg 0..1): 2 output cols (2cp,2cp+1) x 7 rows each.
// Per input row: 4x 8B-aligned ds_read_b64 (w[0..7], window starts at EVEN
// tile col 2cp) feeding 98 fmacs (taps in SGPR). b64 wave access covers both
// bank parities -> ~4 addrs/bank = near the 4-cycle minimum, no conflicts.
// ---------------------------------------------------------------------------
#define TILEW 64
#define TILEH 62

__device__ __forceinline__ float rfl(float v) {
    return __int_as_float(__builtin_amdgcn_readfirstlane(__float_as_int(v)));
}

__global__ __launch_bounds__(256) void conv_kernel(
    const float* __restrict__ x,
    const float* __restrict__ q1, const float* __restrict__ stats1,
    const float* __restrict__ ln1w, const float* __restrict__ ln1b,
    float* __restrict__ out)
{
    __shared__ float tile[TILEH * TILEW];   // tile[r][c] = x[r-3][c-3], 0 outside
    __shared__ float kt[KK];
    int bc   = blockIdx.x;
    int b    = bc / CC;
    int c    = bc - b * CC;
    int tid  = threadIdx.x;
    int lane = tid & 63;
    int wid  = tid >> 6;

    // ---- taps: LN1 + ReLU on q1 ----
    if (tid < KK) {
        float s1  = stats1[b * SPAD + 0];
        float ss1 = stats1[b * SPAD + 1];
        float m = s1 * (1.f / CKK);
        float r = rsqrtf(ss1 * (1.f / CKK) - m * m + 1e-5f);
        float v = (q1[(size_t)bc * KK + tid] - m) * r * ln1w[c * KK + tid]
                  + ln1b[c * KK + tid];
        kt[tid] = v > 0.f ? v : 0.f;
    }

    // ---- zero whole tile, then stage interior at left-pad 3 ----
    for (int i = tid; i < TILEH * TILEW / 4; i += 256)
        ((float4*)tile)[i] = make_float4(0.f, 0.f, 0.f, 0.f);
    __syncthreads();

    const float* src = x + (size_t)bc * HW;
    for (int i = tid; i < HH * 14; i += 256) {
        int r = i / 14;
        int q = i - r * 14;
        float4 v = *(const float4*)(src + r * WW + q * 4);   // aligned global
        float* d = tile + (r + 3) * TILEW + 3 + q * 4;       // pad-3: b32 writes
        d[0] = v.x; d[1] = v.y; d[2] = v.z; d[3] = v.w;
    }
    __syncthreads();

    // ---- taps -> SGPRs ----
    float tap[KK];
#pragma unroll
    for (int t = 0; t < KK; ++t) tap[t] = rfl(kt[t]);

    // ---- lane mapping: 2 cols x 7 rows per lane, no duplication ----
    int cp = lane >> 1; if (cp > 27) cp = 27;   // lanes 56-63: harmless dup
    int rg = lane & 1;
    int o0 = wid * 14 + rg * 7;                 // first output row of this lane
    const float* tb = tile + o0 * TILEW + 2 * cp;   // even col -> 8B aligned

    float acc[KS][2];
#pragma unroll
    for (int t = 0; t < KS; ++t) { acc[t][0] = 0.f; acc[t][1] = 0.f; }

#pragma unroll
    for (int k = 0; k < 13; ++k) {              // input tile rows o0..o0+12
        float w[8];
        *(float2*)(w + 0) = *(const float2*)(tb + k * TILEW + 0);
        *(float2*)(w + 2) = *(const float2*)(tb + k * TILEW + 2);
        *(float2*)(w + 4) = *(const float2*)(tb + k * TILEW + 4);
        *(float2*)(w + 6) = *(const float2*)(tb + k * TILEW + 6);
#pragma unroll
        for (int t = 0; t < KS; ++t) {
            int u = k - t;                      // static after unroll
            if (u >= 0 && u < KS) {
#pragma unroll
                for (int dv = 0; dv < KS; ++dv) {
                    float kv = tap[u * KS + dv];
                    acc[t][0] = fmaf(w[dv],     kv, acc[t][0]);
                    acc[t][1] = fmaf(w[dv + 1], kv, acc[t][1]);
                }
            }
        }
    }

    if (lane < 56) {
        float* ob = out + (size_t)bc * HW;
#pragma unroll
        for (int t = 0; t < KS; ++t)
            *(float2*)(ob + (o0 + t) * WW + 2 * cp) =
                make_float2(acc[t][0], acc[t][1]);
    }
}

// ---------------------------------------------------------------------------
extern "C" void kernel_launch(void* const* d_in, const int* in_sizes, int n_in,
                              void* d_out, int out_size, void* d_ws, size_t ws_size,
                              hipStream_t stream) {
    const float* x    = (const float*)d_in[0];
    const float* ln0w = (const float*)d_in[1];
    const float* ln0b = (const float*)d_in[2];
    const float* w0   = (const float*)d_in[3];
    const float* ln1w = (const float*)d_in[4];
    const float* ln1b = (const float*)d_in[5];
    float* out = (float*)d_out;

    float* p0     = (float*)d_ws;          // [NCELL]
    float* q1     = p0 + NCELL;            // [NCELL]
    float* stats0 = q1 + NCELL;            // [BB*SPAD]
    float* stats1 = stats0 + BB * SPAD;    // [BB*SPAD]

    hipMemsetAsync(stats0, 0, 2 * BB * SPAD * sizeof(float), stream);
    pool_kernel  <<<NCELL / 256, 256, 0, stream>>>(x, p0);
    stats0_kernel<<<BB * 8, 256, 0, stream>>>(p0, stats0);
    mid_kernel   <<<NBC / 8, 512, 0, stream>>>(p0, ln0w, ln0b, w0, stats0, q1, stats1);
    conv_kernel  <<<NBC, 256, 0, stream>>>(x, q1, stats1, ln1w, ln1b, out);
}

// Round 8
// 79.430 us; speedup vs baseline: 1.2619x; 1.0852x over previous
//
#include <hip/hip_runtime.h>

// Problem constants (B,C,H,W,K) = (32,192,56,56,7)
#define BB 32
#define CC 192
#define HH 56
#define WW 56
#define KS 7
#define HW 3136        // 56*56
#define KK 49
#define CKK 9408       // C*K*K
#define PL 8
#define NCELL (BB * CC * KK)   // 301056 = 1176*256
#define NBC (BB * CC)          // 6144
#define SPAD 32                // stats padding: one 128B line per sample

typedef float f2 __attribute__((ext_vector_type(2)));

// ---------------------------------------------------------------------------
// K1: avg pool 56x56 -> 7x7, fused LN0 stats (per-wave reduce + padded
// atomics; 64 | 9408 so each wave lies in one sample b).
// ---------------------------------------------------------------------------
__global__ __launch_bounds__(256) void pool_kernel(const float* __restrict__ x,
                                                   float* __restrict__ p0,
                                                   float* __restrict__ stats0) {
    int idx = blockIdx.x * 256 + threadIdx.x;
    int j = idx % KS;
    int i = (idx / KS) % KS;
    int bc = idx / KK;
    const float* src = x + (size_t)bc * HW + (i * PL) * WW + j * PL;
    float s = 0.f;
#pragma unroll
    for (int a = 0; a < PL; ++a) {
        float4 v0 = *(const float4*)(src + a * WW);
        float4 v1 = *(const float4*)(src + a * WW + 4);
        s += v0.x + v0.y + v0.z + v0.w + v1.x + v1.y + v1.z + v1.w;
    }
    float v = s * (1.f / 64.f);
    p0[idx] = v;

    float sv = v, sq = v * v;
#pragma unroll
    for (int o = 32; o > 0; o >>= 1) {
        sv += __shfl_down(sv, o, 64);
        sq += __shfl_down(sq, o, 64);
    }
    if ((threadIdx.x & 63) == 0) {
        int b = idx / CKK;                    // wave-uniform (64 | 9408)
        atomicAdd(&stats0[b * SPAD + 0], sv);
        atomicAdd(&stats0[b * SPAD + 1], sq);
    }
}

// ---------------------------------------------------------------------------
// K2: LN0-normalize + depthwise 7x7 conv on the 7x7 map, one WAVE per (b,c).
// Produces raw conv output q1 + LN1 stats (padded atomics).
// ---------------------------------------------------------------------------
__global__ __launch_bounds__(512) void mid_kernel(
    const float* __restrict__ p0,
    const float* __restrict__ ln0w, const float* __restrict__ ln0b,
    const float* __restrict__ w0,
    const float* __restrict__ stats0,
    float* __restrict__ q1,
    float* __restrict__ stats1)
{
    int tid  = threadIdx.x;
    int lane = tid & 63;
    int bc   = blockIdx.x * 8 + (tid >> 6);
    int b = bc / CC;
    int c = bc - b * CC;

    float s0   = stats0[b * SPAD + 0];
    float ss0  = stats0[b * SPAD + 1];
    float mean = s0 * (1.f / CKK);
    float rstd = rsqrtf(ss0 * (1.f / CKK) - mean * mean + 1e-5f);

    float val = 0.f;
    if (lane < KK)
        val = (p0[bc * KK + lane] - mean) * rstd * ln0w[c * KK + lane]
              + ln0b[c * KK + lane];

    int i0 = lane / KS;
    int j0 = lane - i0 * KS;
    const float* wc = w0 + c * KK;

    float acc = 0.f;
#pragma unroll
    for (int u = 0; u < KS; ++u) {
        int ii = i0 + u - 3;
#pragma unroll
        for (int v = 0; v < KS; ++v) {
            int jj = j0 + v - 3;
            bool ok = (ii >= 0) && (ii < KS) && (jj >= 0) && (jj < KS);
            int sl = ok ? (ii * KS + jj) : 0;
            float sv = __shfl(val, sl, 64);
            acc += ok ? sv * wc[u * KS + v] : 0.f;
        }
    }
    if (lane >= KK) acc = 0.f;
    if (lane < KK) q1[bc * KK + lane] = acc;

    float s2 = acc, ss2 = acc * acc;
#pragma unroll
    for (int o = 32; o > 0; o >>= 1) {
        s2  += __shfl_down(s2, o, 64);
        ss2 += __shfl_down(ss2, o, 64);
    }
    if (lane == 0) {
        atomicAdd(&stats1[b * SPAD + 0], s2);
        atomicAdd(&stats1[b * SPAD + 1], ss2);
    }
}

// ---------------------------------------------------------------------------
// K3: fused LN1+ReLU taps + per-(b,c) depthwise 7x7 SAME conv.
// R5's proven-clean LDS pattern (whole wave reads one row, consecutive
// dwords), but: 8 adjacent b32 reads/row (compiler merges to ds_read2_b32)
// and v_pk_fma_f32 with SGPR-pair taps (4 packed FMA per (k,t) vs 7 fmac).
// Zero-halo tile [63][64], pad-4: tile[r][c] = x[r-3][c-4]; row 62 = guard.
// ---------------------------------------------------------------------------
#define TILEW 64
#define TILEH 63

__device__ __forceinline__ float rfl(float v) {
    return __int_as_float(__builtin_amdgcn_readfirstlane(__float_as_int(v)));
}

__device__ __forceinline__ void pkfma(f2& acc, f2 v, f2 t) {
    // acc = v * t + acc  (elementwise on both 32-bit halves)
    asm("v_pk_fma_f32 %0, %1, %2, %0" : "+v"(acc) : "v"(v), "s"(t));
}

__global__ __launch_bounds__(256) void conv_kernel(
    const float* __restrict__ x,
    const float* __restrict__ q1, const float* __restrict__ stats1,
    const float* __restrict__ ln1w, const float* __restrict__ ln1b,
    float* __restrict__ out)
{
    __shared__ float tile[TILEH * TILEW];   // tile[r][c] = x[r-3][c-4], 0 outside
    __shared__ float kt[KK];
    int bc   = blockIdx.x;
    int b    = bc / CC;
    int c    = bc - b * CC;
    int tid  = threadIdx.x;
    int lane = tid & 63;
    int wid  = tid >> 6;

    // ---- taps: LN1 + ReLU on q1 ----
    if (tid < KK) {
        float s1  = stats1[b * SPAD + 0];
        float ss1 = stats1[b * SPAD + 1];
        float m = s1 * (1.f / CKK);
        float r = rsqrtf(ss1 * (1.f / CKK) - m * m + 1e-5f);
        float v = (q1[(size_t)bc * KK + tid] - m) * r * ln1w[c * KK + tid]
                  + ln1b[c * KK + tid];
        kt[tid] = v > 0.f ? v : 0.f;
    }

    // ---- zero whole tile (incl. guard row), then stage interior (pad-4) ----
    for (int i = tid; i < TILEH * TILEW / 4; i += 256)
        ((float4*)tile)[i] = make_float4(0.f, 0.f, 0.f, 0.f);
    __syncthreads();

    const float* src = x + (size_t)bc * HW;
    for (int i = tid; i < HH * 14; i += 256) {
        int r = i / 14;
        int q = i - r * 14;
        *(float4*)(tile + (r + 3) * TILEW + 4 + q * 4) =
            *(const float4*)(src + r * WW + q * 4);    // 16B-aligned both sides
    }
    __syncthreads();

    // ---- taps -> SGPR pairs: tp[u][j] = {tap[u*7+2j], tap[u*7+2j+1]} ----
    f2 tp[KS][4];
#pragma unroll
    for (int u = 0; u < KS; ++u) {
#pragma unroll
        for (int j = 0; j < 3; ++j) {
            tp[u][j].x = rfl(kt[u * KS + 2 * j]);
            tp[u][j].y = rfl(kt[u * KS + 2 * j + 1]);
        }
        tp[u][3].x = rfl(kt[u * KS + 6]);
        tp[u][3].y = 0.f;
    }

    // ---- main loop: wave reads one row at a time (conflict-free),
    //      accumulator forwarding into 14 packed accumulators ----
    int r0 = wid * 14;
    const float* trow = tile + r0 * TILEW + lane + 1;

    f2 acc2[14];
#pragma unroll
    for (int o = 0; o < 14; ++o) acc2[o] = (f2){0.f, 0.f};

#pragma unroll
    for (int k = 0; k < 20; ++k) {
        float v[8];
#pragma unroll
        for (int d = 0; d < 8; ++d)
            v[d] = trow[k * TILEW + d];         // 8x b32 -> 4x ds_read2_b32
#pragma unroll
        for (int t = 0; t < 14; ++t) {
            int u = k - t;                      // static after unroll
            if (u >= 0 && u < KS) {
#pragma unroll
                for (int j = 0; j < 4; ++j) {
                    f2 vp = {v[2 * j], v[2 * j + 1]};
                    pkfma(acc2[t], vp, tp[u][j]);
                }
            }
        }
    }

    if (lane < WW) {
        float* ob = out + (size_t)bc * HW;
#pragma unroll
        for (int t = 0; t < 14; ++t)
            ob[(r0 + t) * WW + lane] = acc2[t].x + acc2[t].y;
    }
}

// ---------------------------------------------------------------------------
extern "C" void kernel_launch(void* const* d_in, const int* in_sizes, int n_in,
                              void* d_out, int out_size, void* d_ws, size_t ws_size,
                              hipStream_t stream) {
    const float* x    = (const float*)d_in[0];
    const float* ln0w = (const float*)d_in[1];
    const float* ln0b = (const float*)d_in[2];
    const float* w0   = (const float*)d_in[3];
    const float* ln1w = (const float*)d_in[4];
    const float* ln1b = (const float*)d_in[5];
    float* out = (float*)d_out;

    float* p0     = (float*)d_ws;          // [NCELL]
    float* q1     = p0 + NCELL;            // [NCELL]
    float* stats0 = q1 + NCELL;            // [BB*SPAD]
    float* stats1 = stats0 + BB * SPAD;    // [BB*SPAD]

    hipMemsetAsync(stats0, 0, 2 * BB * SPAD * sizeof(float), stream);
    pool_kernel<<<NCELL / 256, 256, 0, stream>>>(x, p0, stats0);
    mid_kernel <<<NBC / 8, 512, 0, stream>>>(p0, ln0w, ln0b, w0, stats0, q1, stats1);
    conv_kernel<<<NBC, 256, 0, stream>>>(x, q1, stats1, ln1w, ln1b, out);
}